// Round 3
// baseline (448.472 us; speedup 1.0000x reference)
//
#include <hip/hip_runtime.h>
#include <hip/hip_bf16.h>

#define NB   32
#define CIN  128
#define HH   56
#define WW   56
#define COUT 256
#define HW   3136   // 56*56

typedef __bf16 bf16x8 __attribute__((ext_vector_type(8)));
typedef float floatx4 __attribute__((ext_vector_type(4)));

// ---------------- 1) router MLP + softmax(logits/30); gap is pre-summed (needs *1/HW) ----------------
__global__ void router_kernel(const float* __restrict__ gap,
                              const float* __restrict__ w1, const float* __restrict__ b1,
                              const float* __restrict__ w2, const float* __restrict__ b2,
                              float* __restrict__ routing) {
    int b = threadIdx.x;
    if (b >= NB) return;
    const float inv = 1.0f / HW;
    float h[16];
    #pragma unroll
    for (int r = 0; r < 16; ++r) {
        float s = 0.f;
        for (int i = 0; i < CIN; ++i) s += gap[b * CIN + i] * w1[r * CIN + i];
        h[r] = fmaxf(fmaf(s, inv, b1[r]), 0.f);
    }
    float lg[4]; float mx = -1e30f;
    #pragma unroll
    for (int e = 0; e < 4; ++e) {
        float s = b2[e];
        #pragma unroll
        for (int r = 0; r < 16; ++r) s += h[r] * w2[e * 16 + r];
        lg[e] = s * (1.0f / 30.0f);
        mx = fmaxf(mx, lg[e]);
    }
    float den = 0.f, ex[4];
    #pragma unroll
    for (int e = 0; e < 4; ++e) { ex[e] = expf(lg[e] - mx); den += ex[e]; }
    #pragma unroll
    for (int e = 0; e < 4; ++e) routing[b * 4 + e] = ex[e] / den;
}

// ---------------- 2) mix expert kernels -> bf16, layout [b][p][o][i] ----------------
__global__ void mix_kernel(const float* __restrict__ convs,
                           const float* __restrict__ routing,
                           __hip_bfloat16* __restrict__ wmix) {
    int idx = blockIdx.x * 256 + threadIdx.x;       // (b*COUT + o)*CIN + i
    int i = idx & 127;
    int o = (idx >> 7) & 255;
    int b = idx >> 15;
    const float* r = routing + b * 4;
    float r0 = r[0], r1 = r[1], r2 = r[2], r3 = r[3];
    const float* cb = convs + (size_t)(o * CIN + i) * 9;
    const int ES = COUT * CIN * 9;                  // 294912
    float s[9];
    #pragma unroll
    for (int p = 0; p < 9; ++p)
        s[p] = r0 * cb[p] + r1 * cb[p + ES] + r2 * cb[p + 2 * ES] + r3 * cb[p + 3 * ES];
    __hip_bfloat16* wp = wmix + ((size_t)b * 9 * COUT + o) * CIN + i;
    #pragma unroll
    for (int p = 0; p < 9; ++p)
        wp[(size_t)p * COUT * CIN] = __float2bfloat16(s[p]);
}

// ---------------- 3) x: NCHW fp32 -> NHWC bf16 [b][y][x][i], fused GAP partial sums ----------------
__global__ void xpose_kernel(const float* __restrict__ x, __hip_bfloat16* __restrict__ xT,
                             float* __restrict__ gap) {
    int hw0 = blockIdx.x * 64, i0 = blockIdx.y * 64, b = blockIdx.z;
    __shared__ float tile[64][65];
    const float* xp = x + ((size_t)b * CIN + i0) * HW + hw0;
    for (int t = threadIdx.x; t < 4096; t += 256) {
        int ir = t >> 6, c = t & 63;
        tile[ir][c] = xp[(size_t)ir * HW + c];
    }
    __syncthreads();
    __hip_bfloat16* op = xT + ((size_t)b * HW + hw0) * CIN + i0;
    for (int t = threadIdx.x; t < 512; t += 256) {
        int pp = t >> 3, seg = t & 7;
        __hip_bfloat16 tmp[8];
        #pragma unroll
        for (int j = 0; j < 8; ++j) tmp[j] = __float2bfloat16(tile[seg * 8 + j][pp]);
        *(uint4*)(op + (size_t)pp * CIN + seg * 8) = *(uint4*)tmp;
    }
    int ch = threadIdx.x & 63, grp = threadIdx.x >> 6;
    float s = 0.f;
    #pragma unroll
    for (int k = 0; k < 16; ++k) s += tile[ch][grp * 16 + k];
    atomicAdd(gap + b * CIN + i0 + ch, s);
}

// ---------------- 4) dynamic conv: 9 shifted MFMA GEMMs ----------------
// Weights: A-fragments loaded DIRECTLY from global (L2-resident) — no weight LDS,
// no per-tap barriers. Only x halo tile is staged in LDS (2 Cin-chunks, 3 barriers/block).
__global__ __launch_bounds__(256, 3)
void conv_mfma(const __hip_bfloat16* __restrict__ xT,
               const __hip_bfloat16* __restrict__ wmix,
               float* __restrict__ out) {
    __shared__ __align__(16) __hip_bfloat16 xs[180 * 72];   // 10x18 px halo, 64ch, pad->72

    const int tile = blockIdx.x;          // 0..27 = yt*4 + xt
    const int yt = tile >> 2, xt = tile & 3;
    const int mtile = blockIdx.y;         // 0..1
    const int b = blockIdx.z;             // 0..31
    const int y0 = yt * 8, x0 = xt * 16;
    const int tid = threadIdx.x;
    const int lane = tid & 63, wave = tid >> 6;
    const int wm = wave & 1, wn = wave >> 1;
    const int col = lane & 15, quad = lane >> 4;

    floatx4 acc[4][4];
    #pragma unroll
    for (int mt = 0; mt < 4; ++mt)
        #pragma unroll
        for (int nt = 0; nt < 4; ++nt)
            acc[mt][nt] = (floatx4){0.f, 0.f, 0.f, 0.f};

    const __hip_bfloat16* xb = xT + (size_t)b * HW * CIN;
    // per-lane weight base: row = mtile*128 + wm*64 + col, k-offset quad*8
    const __hip_bfloat16* wt = wmix +
        ((size_t)b * 9 * COUT + mtile * 128 + wm * 64 + col) * CIN + quad * 8;

    for (int cc = 0; cc < 2; ++cc) {
        if (cc) __syncthreads();          // previous chunk's reads of xs done
        // stage x halo chunk: 180 px * 8 segs of 8 bf16 (global->VGPR->LDS, transient regs)
        #pragma unroll
        for (int j = 0; j < 6; ++j) {
            int tt = tid + j * 256;
            if (tt < 1440) {
                int pix = tt >> 3, seg = tt & 7;
                int py = pix / 18, px = pix - py * 18;
                int gy = y0 - 1 + py, gx = x0 - 1 + px;
                uint4 v = {0u, 0u, 0u, 0u};
                if ((unsigned)gy < 56u && (unsigned)gx < 56u)
                    v = *(const uint4*)(xb + ((size_t)(gy * 56 + gx) * CIN + cc * 64 + seg * 8));
                *(uint4*)(&xs[pix * 72 + seg * 8]) = v;
            }
        }
        __syncthreads();                  // xs visible to all waves

        #pragma unroll
        for (int p = 0; p < 9; ++p) {
            const int ky = p / 3, kx = p - ky * 3;
            #pragma unroll
            for (int ks = 0; ks < 2; ++ks) {
                bf16x8 af[4], bfr[4];
                #pragma unroll
                for (int mt = 0; mt < 4; ++mt)
                    af[mt] = *(const bf16x8*)(wt +
                        (size_t)(p * COUT + mt * 16) * CIN + cc * 64 + ks * 32);
                #pragma unroll
                for (int nt = 0; nt < 4; ++nt) {
                    int pyy = wn * 4 + nt + ky;   // LDS row 0 = y0-1
                    int pxx = col + kx;
                    bfr[nt] = *(const bf16x8*)(&xs[(pyy * 18 + pxx) * 72 + ks * 32 + quad * 8]);
                }
                #pragma unroll
                for (int mt = 0; mt < 4; ++mt)
                    #pragma unroll
                    for (int nt = 0; nt < 4; ++nt)
                        acc[mt][nt] = __builtin_amdgcn_mfma_f32_16x16x32_bf16(
                            af[mt], bfr[nt], acc[mt][nt], 0, 0, 0);
            }
        }
    }

    // epilogue: C/D layout col=lane&15, row=quad*4+reg
    const int x = x0 + col;
    if (x < 56) {
        #pragma unroll
        for (int mt = 0; mt < 4; ++mt) {
            int o = mtile * 128 + wm * 64 + mt * 16 + quad * 4;
            #pragma unroll
            for (int nt = 0; nt < 4; ++nt) {
                int y = y0 + wn * 4 + nt;
                float* op = out + (((size_t)b * COUT + o) * 56 + y) * 56 + x;
                #pragma unroll
                for (int r = 0; r < 4; ++r)
                    op[(size_t)r * HW] = acc[mt][nt][r];
            }
        }
    }
}

extern "C" void kernel_launch(void* const* d_in, const int* in_sizes, int n_in,
                              void* d_out, int out_size, void* d_ws, size_t ws_size,
                              hipStream_t stream) {
    const float* x     = (const float*)d_in[0];
    const float* convs = (const float*)d_in[1];
    const float* w1    = (const float*)d_in[2];
    const float* b1    = (const float*)d_in[3];
    const float* w2    = (const float*)d_in[4];
    const float* b2    = (const float*)d_in[5];
    float* out = (float*)d_out;

    char* ws = (char*)d_ws;
    float* gap              = (float*)ws;                               // 16384 B
    float* routing          = (float*)(ws + 16384);                     // 512 B
    __hip_bfloat16* xT      = (__hip_bfloat16*)(ws + 16896);            // 25690112 B
    __hip_bfloat16* wmix    = (__hip_bfloat16*)(ws + 16896 + 25690112); // 18874368 B

    hipMemsetAsync(gap, 0, NB * CIN * sizeof(float), stream);
    xpose_kernel <<<dim3(49, 2, NB), 256, 0, stream>>>(x, xT, gap);
    router_kernel<<<1, 64, 0, stream>>>(gap, w1, b1, w2, b2, routing);
    mix_kernel   <<<(NB * COUT * CIN) / 256, 256, 0, stream>>>(convs, routing, wmix);
    conv_mfma    <<<dim3(28, 2, NB), 256, 0, stream>>>(xT, wmix, out);
}

// Round 4
// 398.751 us; speedup vs baseline: 1.1247x; 1.1247x over previous
//
#include <hip/hip_runtime.h>
#include <hip/hip_bf16.h>

#define NB   32
#define CIN  128
#define HH   56
#define WW   56
#define COUT 256
#define HW   3136   // 56*56
#define NCHUNK 576  // weight chunks per (b): 2 mtile * 288

typedef __bf16 bf16x8 __attribute__((ext_vector_type(8)));
typedef float floatx4 __attribute__((ext_vector_type(4)));

// ---------------- 1) router MLP + softmax(logits/30); gap is pre-summed (*1/HW here) ----------------
__global__ void router_kernel(const float* __restrict__ gap,
                              const float* __restrict__ w1, const float* __restrict__ b1,
                              const float* __restrict__ w2, const float* __restrict__ b2,
                              float* __restrict__ routing) {
    int b = threadIdx.x;
    if (b >= NB) return;
    const float inv = 1.0f / HW;
    float h[16];
    #pragma unroll
    for (int r = 0; r < 16; ++r) {
        float s = 0.f;
        for (int i = 0; i < CIN; ++i) s += gap[b * CIN + i] * w1[r * CIN + i];
        h[r] = fmaxf(fmaf(s, inv, b1[r]), 0.f);
    }
    float lg[4]; float mx = -1e30f;
    #pragma unroll
    for (int e = 0; e < 4; ++e) {
        float s = b2[e];
        #pragma unroll
        for (int r = 0; r < 16; ++r) s += h[r] * w2[e * 16 + r];
        lg[e] = s * (1.0f / 30.0f);
        mx = fmaxf(mx, lg[e]);
    }
    float den = 0.f, ex[4];
    #pragma unroll
    for (int e = 0; e < 4; ++e) { ex[e] = expf(lg[e] - mx); den += ex[e]; }
    #pragma unroll
    for (int e = 0; e < 4; ++e) routing[b * 4 + e] = ex[e] / den;
}

// ---------------- 2a) swizzle expert weights into MFMA A-fragment chunk order ----------------
// convT[e][c][lane] 16B chunks; c = mtile*288 + p*32 + cc*16 + ks*8 + mt*2 + wm
// lane=(col,quad) holds row = mtile*128+wm*64+mt*16+col, k = cc*64+ks*32+quad*8 .. +7
__global__ void wswz_kernel(const float* __restrict__ convs,
                            __hip_bfloat16* __restrict__ convT) {
    int t = blockIdx.x * 256 + threadIdx.x;     // (e*576 + c)*64 + lane
    int lane = t & 63;
    int ec = t >> 6;
    int c = ec % NCHUNK, e = ec / NCHUNK;
    int col = lane & 15, quad = lane >> 4;
    int mtile = c / 288, r = c % 288;
    int p  = r >> 5; int r2 = r & 31;
    int cc = r2 >> 4, ks = (r2 >> 3) & 1, mt = (r2 >> 1) & 3, wm = r2 & 1;
    int row = mtile * 128 + wm * 64 + mt * 16 + col;
    int k0  = cc * 64 + ks * 32 + quad * 8;
    const float* src = convs + ((size_t)(e * COUT + row) * CIN + k0) * 9 + p;
    __hip_bfloat16 tmp[8];
    #pragma unroll
    for (int j = 0; j < 8; ++j) tmp[j] = __float2bfloat16(src[j * 9]);
    *(uint4*)(convT + (size_t)t * 8) = *(uint4*)tmp;
}

// ---------------- 2b) mix: wmix[b][c][lane] = sum_e r[b][e] * convT[e][c][lane] ----------------
__global__ void mix_kernel(const __hip_bfloat16* __restrict__ convT,
                           const float* __restrict__ routing,
                           __hip_bfloat16* __restrict__ wmix) {
    int t = blockIdx.x * 256 + threadIdx.x;     // (b*576 + c)*64 + lane
    const int PER_B = NCHUNK * 64;              // 36864 chunk-lanes per b
    int b  = t / PER_B;
    int cl = t - b * PER_B;
    float r0 = routing[b * 4 + 0], r1 = routing[b * 4 + 1];
    float r2 = routing[b * 4 + 2], r3 = routing[b * 4 + 3];
    const int ES = PER_B * 8;                   // 294912 elems per expert
    bf16x8 w0 = *(const bf16x8*)(convT + (size_t)cl * 8);
    bf16x8 w1 = *(const bf16x8*)(convT + (size_t)cl * 8 + ES);
    bf16x8 w2 = *(const bf16x8*)(convT + (size_t)cl * 8 + 2 * ES);
    bf16x8 w3 = *(const bf16x8*)(convT + (size_t)cl * 8 + 3 * ES);
    __hip_bfloat16 o[8];
    #pragma unroll
    for (int j = 0; j < 8; ++j) {
        float s = r0 * (float)w0[j] + r1 * (float)w1[j]
                + r2 * (float)w2[j] + r3 * (float)w3[j];
        o[j] = __float2bfloat16(s);
    }
    *(uint4*)(wmix + (size_t)t * 8) = *(uint4*)o;
}

// ---------------- 3) x: NCHW fp32 -> NHWC bf16 [b][y][x][i], fused GAP partial sums ----------------
__global__ void xpose_kernel(const float* __restrict__ x, __hip_bfloat16* __restrict__ xT,
                             float* __restrict__ gap) {
    int hw0 = blockIdx.x * 64, i0 = blockIdx.y * 64, b = blockIdx.z;
    __shared__ float tile[64][65];
    const float* xp = x + ((size_t)b * CIN + i0) * HW + hw0;
    for (int t = threadIdx.x; t < 4096; t += 256) {
        int ir = t >> 6, c = t & 63;
        tile[ir][c] = xp[(size_t)ir * HW + c];
    }
    __syncthreads();
    __hip_bfloat16* op = xT + ((size_t)b * HW + hw0) * CIN + i0;
    for (int t = threadIdx.x; t < 512; t += 256) {
        int pp = t >> 3, seg = t & 7;
        __hip_bfloat16 tmp[8];
        #pragma unroll
        for (int j = 0; j < 8; ++j) tmp[j] = __float2bfloat16(tile[seg * 8 + j][pp]);
        *(uint4*)(op + (size_t)pp * CIN + seg * 8) = *(uint4*)tmp;
    }
    int ch = threadIdx.x & 63, grp = threadIdx.x >> 6;
    float s = 0.f;
    #pragma unroll
    for (int k = 0; k < 16; ++k) s += tile[ch][grp * 16 + k];
    atomicAdd(gap + b * CIN + i0 + ch, s);
}

// ---------------- 4) dynamic conv: 9 shifted MFMA GEMMs ----------------
// A-fragments loaded directly from global in swizzled chunk order: one coalesced
// dwordx4 per (p,cc,ks,mt) — 4 cache lines/wave, sequential in p. 3 barriers/block.
__global__ __launch_bounds__(256, 3)
void conv_mfma(const __hip_bfloat16* __restrict__ xT,
               const __hip_bfloat16* __restrict__ wmix,
               float* __restrict__ out) {
    __shared__ __align__(16) __hip_bfloat16 xs[180 * 72];   // 10x18 px halo, 64ch, pad->72

    const int tile = blockIdx.x;          // 0..27 = yt*4 + xt
    const int yt = tile >> 2, xt = tile & 3;
    const int mtile = blockIdx.y;         // 0..1
    const int b = blockIdx.z;             // 0..31
    const int y0 = yt * 8, x0 = xt * 16;
    const int tid = threadIdx.x;
    const int lane = tid & 63, wave = tid >> 6;
    const int wm = wave & 1, wn = wave >> 1;
    const int col = lane & 15, quad = lane >> 4;

    floatx4 acc[4][4];
    #pragma unroll
    for (int mt = 0; mt < 4; ++mt)
        #pragma unroll
        for (int nt = 0; nt < 4; ++nt)
            acc[mt][nt] = (floatx4){0.f, 0.f, 0.f, 0.f};

    const __hip_bfloat16* xb = xT + (size_t)b * HW * CIN;
    // per-lane swizzled weight base: chunk = (b*576 + mtile*288 + wm), 512 elems/chunk
    const __hip_bfloat16* wptr = wmix +
        ((size_t)(b * NCHUNK + mtile * 288 + wm)) * 512 + lane * 8;

    for (int cc = 0; cc < 2; ++cc) {
        if (cc) __syncthreads();          // previous chunk's reads of xs done
        #pragma unroll
        for (int j = 0; j < 6; ++j) {
            int tt = tid + j * 256;
            if (tt < 1440) {
                int pix = tt >> 3, seg = tt & 7;
                int py = pix / 18, px = pix - py * 18;
                int gy = y0 - 1 + py, gx = x0 - 1 + px;
                uint4 v = {0u, 0u, 0u, 0u};
                if ((unsigned)gy < 56u && (unsigned)gx < 56u)
                    v = *(const uint4*)(xb + ((size_t)(gy * 56 + gx) * CIN + cc * 64 + seg * 8));
                *(uint4*)(&xs[pix * 72 + seg * 8]) = v;
            }
        }
        __syncthreads();                  // xs visible to all waves

        #pragma unroll
        for (int p = 0; p < 9; ++p) {
            const int ky = p / 3, kx = p - ky * 3;
            #pragma unroll
            for (int ks = 0; ks < 2; ++ks) {
                bf16x8 af[4], bfr[4];
                #pragma unroll
                for (int mt = 0; mt < 4; ++mt)
                    af[mt] = *(const bf16x8*)(wptr +
                        (size_t)(p * 32 + cc * 16 + ks * 8 + mt * 2) * 512);
                #pragma unroll
                for (int nt = 0; nt < 4; ++nt) {
                    int pyy = wn * 4 + nt + ky;   // LDS row 0 = y0-1
                    int pxx = col + kx;
                    bfr[nt] = *(const bf16x8*)(&xs[(pyy * 18 + pxx) * 72 + ks * 32 + quad * 8]);
                }
                #pragma unroll
                for (int mt = 0; mt < 4; ++mt)
                    #pragma unroll
                    for (int nt = 0; nt < 4; ++nt)
                        acc[mt][nt] = __builtin_amdgcn_mfma_f32_16x16x32_bf16(
                            af[mt], bfr[nt], acc[mt][nt], 0, 0, 0);
            }
        }
    }

    // epilogue: C/D layout col=lane&15, row=quad*4+reg
    const int x = x0 + col;
    if (x < 56) {
        #pragma unroll
        for (int mt = 0; mt < 4; ++mt) {
            int o = mtile * 128 + wm * 64 + mt * 16 + quad * 4;
            #pragma unroll
            for (int nt = 0; nt < 4; ++nt) {
                int y = y0 + wn * 4 + nt;
                float* op = out + (((size_t)b * COUT + o) * 56 + y) * 56 + x;
                #pragma unroll
                for (int r = 0; r < 4; ++r)
                    op[(size_t)r * HW] = acc[mt][nt][r];
            }
        }
    }
}

extern "C" void kernel_launch(void* const* d_in, const int* in_sizes, int n_in,
                              void* d_out, int out_size, void* d_ws, size_t ws_size,
                              hipStream_t stream) {
    const float* x     = (const float*)d_in[0];
    const float* convs = (const float*)d_in[1];
    const float* w1    = (const float*)d_in[2];
    const float* b1    = (const float*)d_in[3];
    const float* w2    = (const float*)d_in[4];
    const float* b2    = (const float*)d_in[5];
    float* out = (float*)d_out;

    char* ws = (char*)d_ws;
    float* gap           = (float*)ws;                                  // 16384 B
    float* routing       = (float*)(ws + 16384);                        // 512 B
    __hip_bfloat16* xT   = (__hip_bfloat16*)(ws + 16896);               // 25690112 B
    __hip_bfloat16* wmix = (__hip_bfloat16*)(ws + 16896 + 25690112);    // 18874368 B
    __hip_bfloat16* convT= (__hip_bfloat16*)(ws + 16896 + 25690112 + 18874368); // 2359296 B

    hipMemsetAsync(gap, 0, NB * CIN * sizeof(float), stream);
    wswz_kernel  <<<(4 * NCHUNK * 64) / 256, 256, 0, stream>>>(convs, convT);
    xpose_kernel <<<dim3(49, 2, NB), 256, 0, stream>>>(x, xT, gap);
    router_kernel<<<1, 64, 0, stream>>>(gap, w1, b1, w2, b2, routing);
    mix_kernel   <<<(NB * NCHUNK * 64) / 256, 256, 0, stream>>>(convT, routing, wmix);
    conv_mfma    <<<dim3(28, 2, NB), 256, 0, stream>>>(xT, wmix, out);
}

// Round 5
// 338.533 us; speedup vs baseline: 1.3248x; 1.1779x over previous
//
#include <hip/hip_runtime.h>
#include <hip/hip_bf16.h>

#define NB   32
#define CIN  128
#define HH   56
#define WW   56
#define COUT 256
#define HW   3136   // 56*56
#define NCHUNK 576  // weight chunks per (b): 2 mtile * 288

typedef __bf16 bf16x8 __attribute__((ext_vector_type(8)));
typedef float floatx4 __attribute__((ext_vector_type(4)));

// ---------------- 1) router MLP + softmax(logits/30); gap is pre-summed (*1/HW here) ----------------
__global__ void router_kernel(const float* __restrict__ gap,
                              const float* __restrict__ w1, const float* __restrict__ b1,
                              const float* __restrict__ w2, const float* __restrict__ b2,
                              float* __restrict__ routing) {
    int b = threadIdx.x;
    if (b >= NB) return;
    const float inv = 1.0f / HW;
    float h[16];
    #pragma unroll
    for (int r = 0; r < 16; ++r) {
        float s = 0.f;
        for (int i = 0; i < CIN; ++i) s += gap[b * CIN + i] * w1[r * CIN + i];
        h[r] = fmaxf(fmaf(s, inv, b1[r]), 0.f);
    }
    float lg[4]; float mx = -1e30f;
    #pragma unroll
    for (int e = 0; e < 4; ++e) {
        float s = b2[e];
        #pragma unroll
        for (int r = 0; r < 16; ++r) s += h[r] * w2[e * 16 + r];
        lg[e] = s * (1.0f / 30.0f);
        mx = fmaxf(mx, lg[e]);
    }
    float den = 0.f, ex[4];
    #pragma unroll
    for (int e = 0; e < 4; ++e) { ex[e] = expf(lg[e] - mx); den += ex[e]; }
    #pragma unroll
    for (int e = 0; e < 4; ++e) routing[b * 4 + e] = ex[e] / den;
}

// ---------------- 2a) swizzle expert weights into MFMA A-fragment chunk order ----------------
// convT[e][c][lane] 16B chunks; c = mtile*288 + p*32 + cc*16 + ks*8 + mt*2 + wm
// also zeroes gap[] (runs before xpose in stream order)
__global__ void wswz_kernel(const float* __restrict__ convs,
                            __hip_bfloat16* __restrict__ convT,
                            float* __restrict__ gap) {
    if (blockIdx.x < 16) gap[blockIdx.x * 256 + threadIdx.x] = 0.f;
    int t = blockIdx.x * 256 + threadIdx.x;     // (e*576 + c)*64 + lane
    int lane = t & 63;
    int ec = t >> 6;
    int c = ec % NCHUNK, e = ec / NCHUNK;
    int col = lane & 15, quad = lane >> 4;
    int mtile = c / 288, r = c % 288;
    int p  = r >> 5; int r2 = r & 31;
    int cc = r2 >> 4, ks = (r2 >> 3) & 1, mt = (r2 >> 1) & 3, wm = r2 & 1;
    int row = mtile * 128 + wm * 64 + mt * 16 + col;
    int k0  = cc * 64 + ks * 32 + quad * 8;
    const float* src = convs + ((size_t)(e * COUT + row) * CIN + k0) * 9 + p;
    __hip_bfloat16 tmp[8];
    #pragma unroll
    for (int j = 0; j < 8; ++j) tmp[j] = __float2bfloat16(src[j * 9]);
    *(uint4*)(convT + (size_t)t * 8) = *(uint4*)tmp;
}

// ---------------- 2b) mix: wmix[b][c][lane] = sum_e r[b][e] * convT[e][c][lane] ----------------
__global__ void mix_kernel(const __hip_bfloat16* __restrict__ convT,
                           const float* __restrict__ routing,
                           __hip_bfloat16* __restrict__ wmix) {
    int t = blockIdx.x * 256 + threadIdx.x;     // (b*576 + c)*64 + lane
    const int PER_B = NCHUNK * 64;              // 36864 chunk-lanes per b
    int b  = t / PER_B;
    int cl = t - b * PER_B;
    float r0 = routing[b * 4 + 0], r1 = routing[b * 4 + 1];
    float r2 = routing[b * 4 + 2], r3 = routing[b * 4 + 3];
    const int ES = PER_B * 8;                   // 294912 elems per expert
    bf16x8 w0 = *(const bf16x8*)(convT + (size_t)cl * 8);
    bf16x8 w1 = *(const bf16x8*)(convT + (size_t)cl * 8 + ES);
    bf16x8 w2 = *(const bf16x8*)(convT + (size_t)cl * 8 + 2 * ES);
    bf16x8 w3 = *(const bf16x8*)(convT + (size_t)cl * 8 + 3 * ES);
    __hip_bfloat16 o[8];
    #pragma unroll
    for (int j = 0; j < 8; ++j) {
        float s = r0 * (float)w0[j] + r1 * (float)w1[j]
                + r2 * (float)w2[j] + r3 * (float)w3[j];
        o[j] = __float2bfloat16(s);
    }
    *(uint4*)(wmix + (size_t)t * 8) = *(uint4*)o;
}

// ---------------- 3) x: NCHW fp32 -> NHWC bf16 [b][y][x][i], fused GAP partial sums ----------------
__global__ void xpose_kernel(const float* __restrict__ x, __hip_bfloat16* __restrict__ xT,
                             float* __restrict__ gap) {
    int hw0 = blockIdx.x * 64, i0 = blockIdx.y * 64, b = blockIdx.z;
    __shared__ float tile[64][65];
    const float* xp = x + ((size_t)b * CIN + i0) * HW + hw0;
    for (int t = threadIdx.x; t < 4096; t += 256) {
        int ir = t >> 6, c = t & 63;
        tile[ir][c] = xp[(size_t)ir * HW + c];
    }
    __syncthreads();
    __hip_bfloat16* op = xT + ((size_t)b * HW + hw0) * CIN + i0;
    for (int t = threadIdx.x; t < 512; t += 256) {
        int pp = t >> 3, seg = t & 7;
        __hip_bfloat16 tmp[8];
        #pragma unroll
        for (int j = 0; j < 8; ++j) tmp[j] = __float2bfloat16(tile[seg * 8 + j][pp]);
        *(uint4*)(op + (size_t)pp * CIN + seg * 8) = *(uint4*)tmp;
    }
    int ch = threadIdx.x & 63, grp = threadIdx.x >> 6;
    float s = 0.f;
    #pragma unroll
    for (int k = 0; k < 16; ++k) s += tile[ch][grp * 16 + k];
    atomicAdd(gap + b * CIN + i0 + ch, s);
}

// ---------------- 4) dynamic conv: 9 shifted MFMA GEMMs, software-pipelined ----------------
// x halo (all 128 ch) staged ONCE -> 1 barrier/block. Weights streamed from global
// (swizzled layout, coalesced) with depth-2 rotating prefetch; x fragments ping-pong.
#define XSTRIDE 136   // 128 ch + 8 pad elems (16B-aligned rows, 2-way-free banks)
__global__ __launch_bounds__(256, 2)
void conv_mfma(const __hip_bfloat16* __restrict__ xT,
               const __hip_bfloat16* __restrict__ wmix,
               float* __restrict__ out) {
    __shared__ __align__(16) __hip_bfloat16 xs[180 * XSTRIDE];   // 48.96 KB

    const int tile = blockIdx.x;          // 0..27 = yt*4 + xt
    const int yt = tile >> 2, xt = tile & 3;
    const int mtile = blockIdx.y;         // 0..1
    const int b = blockIdx.z;             // 0..31
    const int y0 = yt * 8, x0 = xt * 16;
    const int tid = threadIdx.x;
    const int lane = tid & 63, wave = tid >> 6;
    const int wm = wave & 1, wn = wave >> 1;
    const int col = lane & 15, quad = lane >> 4;

    const __hip_bfloat16* xb = xT + (size_t)b * HW * CIN;
    const __hip_bfloat16* wptr = wmix +
        ((size_t)(b * NCHUNK + mtile * 288 + wm)) * 512 + lane * 8;

    // ---- stage full x halo tile (180 px x 128 ch) once ----
    #pragma unroll
    for (int j = 0; j < 12; ++j) {
        int tt = tid + j * 256;
        if (tt < 2880) {                       // 180 px * 16 segs
            int pix = tt >> 4, seg = tt & 15;
            int py = pix / 18, px = pix - py * 18;
            int gy = y0 - 1 + py, gx = x0 - 1 + px;
            uint4 v = {0u, 0u, 0u, 0u};
            if ((unsigned)gy < 56u && (unsigned)gx < 56u)
                v = *(const uint4*)(xb + ((size_t)(gy * 56 + gx) * CIN + seg * 8));
            *(uint4*)(&xs[pix * XSTRIDE + seg * 8]) = v;
        }
    }

    floatx4 acc[4][4];
    #pragma unroll
    for (int mt = 0; mt < 4; ++mt)
        #pragma unroll
        for (int nt = 0; nt < 4; ++nt)
            acc[mt][nt] = (floatx4){0.f, 0.f, 0.f, 0.f};

    bf16x8 af[3][4];   // rotating weight prefetch (2 steps ahead)
    bf16x8 bfr[2][4];  // ping-pong x fragments (1 step ahead)

    auto loadaf = [&](int s, bf16x8* dst) {
        const int cc = s / 18, pp = (s % 18) >> 1, ks = s & 1;
        #pragma unroll
        for (int mt = 0; mt < 4; ++mt)
            dst[mt] = *(const bf16x8*)(wptr +
                (size_t)(pp * 32 + cc * 16 + ks * 8 + mt * 2) * 512);
    };
    auto loadbfr = [&](int s, bf16x8* dst) {
        const int cc = s / 18, pp = (s % 18) >> 1, ks = s & 1;
        const int ky = pp / 3, kx = pp - ky * 3;
        #pragma unroll
        for (int nt = 0; nt < 4; ++nt) {
            int pyy = wn * 4 + nt + ky;       // LDS row 0 = y0-1
            int pxx = col + kx;
            dst[nt] = *(const bf16x8*)(&xs[(pyy * 18 + pxx) * XSTRIDE +
                                           cc * 64 + ks * 32 + quad * 8]);
        }
    };

    loadaf(0, af[0]);
    loadaf(1, af[1]);
    __syncthreads();                          // xs visible (the only barrier)
    loadbfr(0, bfr[0]);

    #pragma unroll
    for (int s = 0; s < 36; ++s) {
        if (s + 2 < 36) loadaf(s + 2, af[(s + 2) % 3]);
        if (s + 1 < 36) loadbfr(s + 1, bfr[(s + 1) & 1]);
        #pragma unroll
        for (int mt = 0; mt < 4; ++mt)
            #pragma unroll
            for (int nt = 0; nt < 4; ++nt)
                acc[mt][nt] = __builtin_amdgcn_mfma_f32_16x16x32_bf16(
                    af[s % 3][mt], bfr[s & 1][nt], acc[mt][nt], 0, 0, 0);
    }

    // epilogue: C/D layout col=lane&15, row=quad*4+reg
    const int x = x0 + col;
    if (x < 56) {
        #pragma unroll
        for (int mt = 0; mt < 4; ++mt) {
            int o = mtile * 128 + wm * 64 + mt * 16 + quad * 4;
            #pragma unroll
            for (int nt = 0; nt < 4; ++nt) {
                int y = y0 + wn * 4 + nt;
                float* op = out + (((size_t)b * COUT + o) * 56 + y) * 56 + x;
                #pragma unroll
                for (int r = 0; r < 4; ++r)
                    op[(size_t)r * HW] = acc[mt][nt][r];
            }
        }
    }
}

extern "C" void kernel_launch(void* const* d_in, const int* in_sizes, int n_in,
                              void* d_out, int out_size, void* d_ws, size_t ws_size,
                              hipStream_t stream) {
    const float* x     = (const float*)d_in[0];
    const float* convs = (const float*)d_in[1];
    const float* w1    = (const float*)d_in[2];
    const float* b1    = (const float*)d_in[3];
    const float* w2    = (const float*)d_in[4];
    const float* b2    = (const float*)d_in[5];
    float* out = (float*)d_out;

    char* ws = (char*)d_ws;
    float* gap           = (float*)ws;                                  // 16384 B
    float* routing       = (float*)(ws + 16384);                        // 512 B
    __hip_bfloat16* xT   = (__hip_bfloat16*)(ws + 16896);               // 25690112 B
    __hip_bfloat16* wmix = (__hip_bfloat16*)(ws + 16896 + 25690112);    // 18874368 B
    __hip_bfloat16* convT= (__hip_bfloat16*)(ws + 16896 + 25690112 + 18874368); // 2359296 B

    wswz_kernel  <<<(4 * NCHUNK * 64) / 256, 256, 0, stream>>>(convs, convT, gap);
    xpose_kernel <<<dim3(49, 2, NB), 256, 0, stream>>>(x, xT, gap);
    router_kernel<<<1, 64, 0, stream>>>(gap, w1, b1, w2, b2, routing);
    mix_kernel   <<<(NB * NCHUNK * 64) / 256, 256, 0, stream>>>(convT, routing, wmix);
    conv_mfma    <<<dim3(28, 2, NB), 256, 0, stream>>>(xT, wmix, out);
}